// Round 5
// baseline (148.841 us; speedup 1.0000x reference)
//
#include <hip/hip_runtime.h>

#define ZD_ 64
#define PD_ 16
#define DH_ 128

// ---------------------------------------------------------------------------
// K0: hidT[d][r] = relu([z_all | pde] @ W1^T + b1), TRANSPOSED output.
// ---------------------------------------------------------------------------
__global__ void hid_kernel(const float* __restrict__ z_all,
                           const float* __restrict__ W1,
                           const float* __restrict__ b1,
                           const float* __restrict__ pde,
                           float* __restrict__ hidT) {
    int gid = blockIdx.x * 256 + threadIdx.x;   // 8192 outputs
    int d = gid >> 6;                            // hidden unit (wave-uniform)
    int r = gid & 63;                            // z row
    const float* w = W1 + d * (ZD_ + PD_);
    const float* z = z_all + r * ZD_;
    float acc = b1[d];
    #pragma unroll 8
    for (int c = 0; c < ZD_; ++c) acc += z[c] * w[c];
    #pragma unroll
    for (int c = 0; c < PD_; ++c) acc += pde[c] * w[ZD_ + c];
    hidT[d * 64 + r] = fmaxf(acc, 0.0f);
}

// ---------------------------------------------------------------------------
// K1 fused: block = (ob, ibp16), n0 = ob*576 + ibp*36 (36 W2 rows = 4 ib x 9 k).
// Grid 1024 x 256 threads. LDS 53.8 KB -> 2 blocks/CU -> TWO scheduling
// rounds: round-2 stage+dot overlaps round-1 store drain (s_endpgm frees
// the slot before vmcnt drains). This was the R4 gap: one lockstep round
// left HBM idle during dot and LDS idle during the write tail.
//
// Thread = (cp 0..31: cell pair, ibl 0..3, ks 0..1 K-half).
//   Register tile: 2 cells x 9 k-rows x K-half-64. Per 4-c chunk:
//   4 b64 (hidT pair) + 9 b128 (W2) feed 72 fmacs -> VALU-bound (2304 vs
//   ~2100 LDS cyc/wave). K-split combined via padded s_red (stride 19).
// Phase-1 LDS: s_w2[36][132] (19.0 KB) + s_hT[128][68] (34.8 KB).
// Phase-2 (aliased after barrier): s_exe[64][37], s_red[128][19], s_un[64][36].
// Epilogue: 64 runs x 81 float4 per block, coalesced, 16B-aligned
//   (i0 = kb*64 + ibp*4 ≡ 0 mod 4).
// ---------------------------------------------------------------------------
#define SMEM_FLOATS 13456   // 53,824 bytes = s_w2 4752 + s_hT 8704

__global__ __launch_bounds__(256) void fused_kernel(
        const float* __restrict__ hidT,
        const float* __restrict__ W2,
        const float* __restrict__ b2,
        const float* __restrict__ unet,
        float* __restrict__ out) {
    __shared__ __align__(16) float smem[SMEM_FLOATS];
    float* s_w2 = smem;            // 36*132 = 4752 floats
    float* s_hT = smem + 4752;     // 128*68 = 8704 floats

    int tid = threadIdx.x;
    int b   = blockIdx.x;
    int ob  = b >> 4;              // 0..63
    int ibp = b & 15;              // 0..15
    int n0  = ob * 576 + ibp * 36;

    // --- stage W2: 36 contiguous rows = 1152 float4 ---
    const float4* g4 = reinterpret_cast<const float4*>(W2 + (size_t)n0 * DH_);
    #pragma unroll
    for (int t = 0; t < 5; ++t) {
        int j = t * 256 + tid;
        if (j < 1152) {
            int row = j >> 5;          // 0..35
            int c4  = j & 31;
            *reinterpret_cast<float4*>(&s_w2[row * 132 + c4 * 4]) = g4[j];
        }
    }
    // --- stage hidT: 2048 float4 ---
    const float4* h4g = reinterpret_cast<const float4*>(hidT);
    #pragma unroll
    for (int t = 0; t < 8; ++t) {
        int j  = t * 256 + tid;
        int d  = j >> 4;           // k index 0..127
        int r4 = j & 15;           // cell-quad
        *reinterpret_cast<float4*>(&s_hT[d * 68 + r4 * 4]) = h4g[j];
    }

    int cp  = tid & 31;            // cells 2cp, 2cp+1
    int ibl = (tid >> 5) & 3;      // local ib 0..3
    int ks  = tid >> 7;            // K-half (wave-uniform)

    float2 acc[9];
    if (ks == 0) {
        #pragma unroll
        for (int kk = 0; kk < 9; ++kk) {
            float bv = b2[n0 + ibl * 9 + kk];
            acc[kk] = make_float2(bv, bv);
        }
    } else {
        #pragma unroll
        for (int kk = 0; kk < 9; ++kk) acc[kk] = make_float2(0.f, 0.f);
    }
    __syncthreads();

    // --- dot: 16 chunks of 4 c-values over this thread's K-half ---
    const float* wbase = s_w2 + ibl * 9 * 132 + ks * 64;
    const float* hbase = s_hT + ks * 64 * 68 + 2 * cp;
    #pragma unroll 4
    for (int cc = 0; cc < 64; cc += 4) {
        float2 h0 = *reinterpret_cast<const float2*>(&hbase[(cc + 0) * 68]);
        float2 h1 = *reinterpret_cast<const float2*>(&hbase[(cc + 1) * 68]);
        float2 h2 = *reinterpret_cast<const float2*>(&hbase[(cc + 2) * 68]);
        float2 h3 = *reinterpret_cast<const float2*>(&hbase[(cc + 3) * 68]);
        #pragma unroll
        for (int kk = 0; kk < 9; ++kk) {
            float4 w = *reinterpret_cast<const float4*>(&wbase[kk * 132 + cc]);
            acc[kk].x += h0.x * w.x + h1.x * w.y + h2.x * w.z + h3.x * w.w;
            acc[kk].y += h0.y * w.x + h1.y * w.y + h2.y * w.z + h3.y * w.w;
        }
    }
    __syncthreads();   // all s_w2 / s_hT reads complete -> safe to alias

    float* s_exe = smem;           // 64*37 = 2368 floats
    float* s_red = smem + 2368;    // 128*19 = 2432 floats
    float* s_un  = smem + 4816;    // 64*36 = 2304 floats (ends 7120 < 13456)

    if (ks == 1) {                 // waves 2,3: dump partials
        int slot = tid & 127;
        #pragma unroll
        for (int kk = 0; kk < 9; ++kk) {
            s_red[slot * 19 + kk]     = acc[kk].x;
            s_red[slot * 19 + 9 + kk] = acc[kk].y;
        }
    }
    // stage unet (all threads): 64 cells x 9 float4 = 576 float4
    for (int j = tid; j < 576; j += 256) {
        int cell = j / 9;
        int q    = j - cell * 9;
        int hh = cell >> 3, kb = cell & 7;
        size_t gb = ((size_t)((hh * 64 + ob) * 512 + kb * 64 + ibp * 4)) * 9;
        *reinterpret_cast<float4*>(&s_un[cell * 36 + q * 4]) =
            *reinterpret_cast<const float4*>(unet + gb + q * 4);
    }
    __syncthreads();

    if (ks == 0) {                 // waves 0,1: combine + write s_exe
        #pragma unroll
        for (int kk = 0; kk < 9; ++kk) {
            int col = ibl * 9 + kk;
            s_exe[(2 * cp + 0) * 37 + col] = acc[kk].x + s_red[tid * 19 + kk];
            s_exe[(2 * cp + 1) * 37 + col] = acc[kk].y + s_red[tid * 19 + 9 + kk];
        }
    }
    __syncthreads();

    // --- epilogue: 64 runs x 81 float4, coalesced stores ---
    for (int idx = tid; idx < 5184; idx += 256) {
        int cell = idx / 81;
        int q    = idx - cell * 81;
        float4 v;
        float* vp = &v.x;
        #pragma unroll
        for (int j2 = 0; j2 < 4; ++j2) {
            int e    = q * 4 + j2;         // 0..323 within run
            int ibl2 = e / 81;
            int rem  = e - ibl2 * 81;
            int k    = rem / 9;
            int l    = rem - k * 9;
            vp[j2] = s_exe[cell * 37 + ibl2 * 9 + k]
                   * s_un [cell * 36 + ibl2 * 9 + l];
        }
        int hh = cell >> 3, kb = cell & 7;
        size_t gb = ((size_t)((hh * 64 + ob) * 512 + kb * 64 + ibp * 4)) * 81;
        reinterpret_cast<float4*>(out + gb)[q] = v;   // 16B-aligned
    }
}

// ---------------------------------------------------------------------------
extern "C" void kernel_launch(void* const* d_in, const int* in_sizes, int n_in,
                              void* d_out, int out_size, void* d_ws, size_t ws_size,
                              hipStream_t stream) {
    const float* z_all = (const float*)d_in[0];  // [64,64]
    const float* W1    = (const float*)d_in[1];  // [128,80]
    const float* b1    = (const float*)d_in[2];  // [128]
    const float* W2    = (const float*)d_in[3];  // [36864,128]
    const float* b2    = (const float*)d_in[4];  // [36864]
    const float* unet  = (const float*)d_in[5];  // [512,512,9]
    const float* pde   = (const float*)d_in[6];  // [16]
    float* out = (float*)d_out;                  // [512,512,9,9]

    float* hidT = (float*)d_ws;                  // 8192 floats, [128][64]

    hid_kernel<<<32, 256, 0, stream>>>(z_all, W1, b1, pde, hidT);
    fused_kernel<<<1024, 256, 0, stream>>>(hidT, W2, b2, unet, out);
}

// Round 6
// 144.248 us; speedup vs baseline: 1.0318x; 1.0318x over previous
//
#include <hip/hip_runtime.h>

#define ZD_ 64
#define PD_ 16
#define DH_ 128

// ---------------------------------------------------------------------------
// K0: hidT[d][r] = relu([z_all | pde] @ W1^T + b1), TRANSPOSED output [128][64].
// ---------------------------------------------------------------------------
__global__ void hid_kernel(const float* __restrict__ z_all,
                           const float* __restrict__ W1,
                           const float* __restrict__ b1,
                           const float* __restrict__ pde,
                           float* __restrict__ hidT) {
    int gid = blockIdx.x * 256 + threadIdx.x;   // 8192 outputs
    int d = gid >> 6;                            // hidden unit (wave-uniform)
    int r = gid & 63;                            // z row
    const float* w = W1 + d * (ZD_ + PD_);
    const float* z = z_all + r * ZD_;
    float acc = b1[d];
    #pragma unroll 8
    for (int c = 0; c < ZD_; ++c) acc += z[c] * w[c];
    #pragma unroll
    for (int c = 0; c < PD_; ++c) acc += pde[c] * w[ZD_ + c];
    hidT[d * 64 + r] = fmaxf(acc, 0.0f);
}

// ---------------------------------------------------------------------------
// K1 fused: block = (ob 0..63, ibp 0..15), n0 = ob*576 + ibp*36 (4 ib x 9 k).
// Grid 1024 x 256 threads (4 waves). LDS = 50.0 KB exactly -> 3 blocks/CU
// (12 waves/CU, up from R4's 8) and 1.33 scheduling rounds.
//
// Thread map (bank-derived, preserves R4's proven dot efficiency):
//   lane = tid&63: cg = lane&15 (4 cells 4cg..4cg+3), ibl = lane>>4 (0..3).
//   wave = tid>>6 = ks (K-QUARTER, wave-uniform -> h-read banks don't fold).
// Dot per thread: 4 cells x 9 k-rows x 32 c in 8 chunks of 4c:
//   4x b128 hidT (stride 64: 16 distinct f4 over 32 banks, 2-way = free,
//   since ks uniform + ibl broadcast) + 9x b128 W2 (stride 128: addr varies
//   only by ibl -> 4-addr broadcast, conflict-free unpadded).
//   Same LDS-cyc/fmac as R4 (the R5 regression was 2-cell b64 reads).
// K-combine: waves 1..3 dump 36 partials to s_red (stride 37, coprime 32 ->
//   conflict-free); wave 0 combines + adds bias -> s_exe. unet staged
//   concurrently by all threads.
// Phase-1 LDS: s_w2[36][128]=4608 fl + s_hT[128][64]=8192 fl = 12800 fl.
// Phase-2 (aliased): s_red 3*64*37=7104 + s_exe 64*37=2368 + s_un 64*36=2304
//   = 11776 fl <= 12800. Epilogue: 64 runs x 81 float4, coalesced,
//   16B-aligned (i0 = kb*64 + ibp*4 ≡ 0 mod 4).
// ---------------------------------------------------------------------------
#define SMEM_FLOATS 12800   // 51,200 B = 50.0 KB -> 3 blocks/CU

__global__ __launch_bounds__(256, 3) void fused_kernel(
        const float* __restrict__ hidT,
        const float* __restrict__ W2,
        const float* __restrict__ b2,
        const float* __restrict__ unet,
        float* __restrict__ out) {
    __shared__ __align__(16) float smem[SMEM_FLOATS];
    float* s_w2 = smem;            // [36][128] = 4608 floats
    float* s_hT = smem + 4608;     // [128][64] = 8192 floats

    int tid = threadIdx.x;
    int b   = blockIdx.x;
    int ob  = b >> 4;              // 0..63
    int ibp = b & 15;              // 0..15
    int n0  = ob * 576 + ibp * 36;

    int lane = tid & 63;
    int wave = tid >> 6;           // = ks (K-quarter), wave-uniform
    int cg   = lane & 15;          // cell quad: cells 4cg..4cg+3
    int ibl  = lane >> 4;          // 0..3 local ib

    // early bias load (used by wave 0 at combine; harmless elsewhere)
    float b2v[9];
    #pragma unroll
    for (int kk = 0; kk < 9; ++kk) b2v[kk] = b2[n0 + ibl * 9 + kk];

    // --- stage W2: 36 contiguous rows = 1152 float4 ---
    const float4* g4 = reinterpret_cast<const float4*>(W2 + (size_t)n0 * DH_);
    #pragma unroll
    for (int t = 0; t < 5; ++t) {
        int j = t * 256 + tid;
        if (j < 1152) {
            int row = j >> 5;          // 0..35
            int c4  = j & 31;
            *reinterpret_cast<float4*>(&s_w2[row * 128 + c4 * 4]) = g4[j];
        }
    }
    // --- stage hidT: 2048 float4 (stride 64; write-conflict small, one-time) ---
    const float4* h4g = reinterpret_cast<const float4*>(hidT);
    #pragma unroll
    for (int t = 0; t < 8; ++t) {
        int j  = t * 256 + tid;
        int d  = j >> 4;           // k index 0..127
        int r4 = j & 15;           // cell-quad
        *reinterpret_cast<float4*>(&s_hT[d * 64 + r4 * 4]) = h4g[j];
    }
    __syncthreads();               // B1

    // --- dot: this wave's K-quarter [wave*32, wave*32+32) ---
    const float* wb = s_w2 + wave * 32;               // + (ibl*9+kk)*128 + cc
    const float* hb = s_hT + wave * 32 * 64 + 4 * cg; // + (cc+i)*64
    float4 acc[9];
    #pragma unroll
    for (int kk = 0; kk < 9; ++kk) acc[kk] = make_float4(0.f, 0.f, 0.f, 0.f);

    #pragma unroll 2
    for (int cc = 0; cc < 32; cc += 4) {
        float4 h0 = *reinterpret_cast<const float4*>(&hb[(cc + 0) * 64]);
        float4 h1 = *reinterpret_cast<const float4*>(&hb[(cc + 1) * 64]);
        float4 h2 = *reinterpret_cast<const float4*>(&hb[(cc + 2) * 64]);
        float4 h3 = *reinterpret_cast<const float4*>(&hb[(cc + 3) * 64]);
        #pragma unroll
        for (int kk = 0; kk < 9; ++kk) {
            float4 w = *reinterpret_cast<const float4*>(
                           &wb[(ibl * 9 + kk) * 128 + cc]);
            acc[kk].x += h0.x * w.x + h1.x * w.y + h2.x * w.z + h3.x * w.w;
            acc[kk].y += h0.y * w.x + h1.y * w.y + h2.y * w.z + h3.y * w.w;
            acc[kk].z += h0.z * w.x + h1.z * w.y + h2.z * w.z + h3.z * w.w;
            acc[kk].w += h0.w * w.x + h1.w * w.y + h2.w * w.z + h3.w * w.w;
        }
    }
    __syncthreads();               // B2: s_w2/s_hT reads done -> alias safe

    float* s_red = smem;           // 3*64*37 = 7104 floats
    float* s_exe = smem + 7104;    // 64*37   = 2368 floats
    float* s_un  = smem + 9472;    // 64*36   = 2304 floats (ends 11776)

    if (wave != 0) {               // waves 1..3: dump K-partials
        int base = ((wave - 1) * 64 + lane) * 37;
        #pragma unroll
        for (int kk = 0; kk < 9; ++kk) {
            s_red[base +      kk] = acc[kk].x;
            s_red[base +  9 + kk] = acc[kk].y;
            s_red[base + 18 + kk] = acc[kk].z;
            s_red[base + 27 + kk] = acc[kk].w;
        }
    }
    // stage unet (all threads): 64 cells x 9 float4 = 576 float4
    for (int j = tid; j < 576; j += 256) {
        int cell = j / 9;
        int q    = j - cell * 9;
        int hh = cell >> 3, kb = cell & 7;
        size_t gb = ((size_t)((hh * 64 + ob) * 512 + kb * 64 + ibp * 4)) * 9;
        *reinterpret_cast<float4*>(&s_un[cell * 36 + q * 4]) =
            *reinterpret_cast<const float4*>(unet + gb + q * 4);
    }
    __syncthreads();               // B3: dumps visible

    if (wave == 0) {               // combine 4 K-quarters + bias -> s_exe
        #pragma unroll
        for (int kk = 0; kk < 9; ++kk) {
            float bv = b2v[kk];
            int col  = ibl * 9 + kk;
            float rx = acc[kk].x + s_red[(      lane) * 37 +      kk]
                                 + s_red[( 64 + lane) * 37 +      kk]
                                 + s_red[(128 + lane) * 37 +      kk];
            float ry = acc[kk].y + s_red[(      lane) * 37 +  9 + kk]
                                 + s_red[( 64 + lane) * 37 +  9 + kk]
                                 + s_red[(128 + lane) * 37 +  9 + kk];
            float rz = acc[kk].z + s_red[(      lane) * 37 + 18 + kk]
                                 + s_red[( 64 + lane) * 37 + 18 + kk]
                                 + s_red[(128 + lane) * 37 + 18 + kk];
            float rw = acc[kk].w + s_red[(      lane) * 37 + 27 + kk]
                                 + s_red[( 64 + lane) * 37 + 27 + kk]
                                 + s_red[(128 + lane) * 37 + 27 + kk];
            s_exe[(4 * cg + 0) * 37 + col] = rx + bv;
            s_exe[(4 * cg + 1) * 37 + col] = ry + bv;
            s_exe[(4 * cg + 2) * 37 + col] = rz + bv;
            s_exe[(4 * cg + 3) * 37 + col] = rw + bv;
        }
    }
    __syncthreads();               // B4: s_exe ready

    // --- epilogue: 64 runs x 81 float4, coalesced stores ---
    for (int idx = tid; idx < 5184; idx += 256) {
        int cell = idx / 81;
        int q    = idx - cell * 81;
        float4 v;
        float* vp = &v.x;
        #pragma unroll
        for (int j2 = 0; j2 < 4; ++j2) {
            int e    = q * 4 + j2;         // 0..323 within run
            int ibl2 = e / 81;
            int rem  = e - ibl2 * 81;
            int k    = rem / 9;
            int l    = rem - k * 9;
            vp[j2] = s_exe[cell * 37 + ibl2 * 9 + k]
                   * s_un [cell * 36 + ibl2 * 9 + l];
        }
        int hh = cell >> 3, kb = cell & 7;
        size_t gb = ((size_t)((hh * 64 + ob) * 512 + kb * 64 + ibp * 4)) * 81;
        reinterpret_cast<float4*>(out + gb)[q] = v;   // 16B-aligned
    }
}

// ---------------------------------------------------------------------------
extern "C" void kernel_launch(void* const* d_in, const int* in_sizes, int n_in,
                              void* d_out, int out_size, void* d_ws, size_t ws_size,
                              hipStream_t stream) {
    const float* z_all = (const float*)d_in[0];  // [64,64]
    const float* W1    = (const float*)d_in[1];  // [128,80]
    const float* b1    = (const float*)d_in[2];  // [128]
    const float* W2    = (const float*)d_in[3];  // [36864,128]
    const float* b2    = (const float*)d_in[4];  // [36864]
    const float* unet  = (const float*)d_in[5];  // [512,512,9]
    const float* pde   = (const float*)d_in[6];  // [16]
    float* out = (float*)d_out;                  // [512,512,9,9]

    float* hidT = (float*)d_ws;                  // 8192 floats, [128][64]

    hid_kernel<<<32, 256, 0, stream>>>(z_all, W1, b1, pde, hidT);
    fused_kernel<<<1024, 256, 0, stream>>>(hidT, W2, b2, unet, out);
}

// Round 7
// 139.007 us; speedup vs baseline: 1.0707x; 1.0377x over previous
//
#include <hip/hip_runtime.h>

#define ZD_ 64
#define PD_ 16
#define DH_ 128

// ---------------------------------------------------------------------------
// K0: hidT[d][r] = relu([z_all | pde] @ W1^T + b1), TRANSPOSED output.
// gid -> d = gid>>6 (wave-uniform: W1 row via scalar loads), r = gid&63.
// Writes hidT[d*64+r]: consecutive lanes -> consecutive r -> coalesced.
// ---------------------------------------------------------------------------
__global__ void hid_kernel(const float* __restrict__ z_all,
                           const float* __restrict__ W1,
                           const float* __restrict__ b1,
                           const float* __restrict__ pde,
                           float* __restrict__ hidT) {
    int gid = blockIdx.x * 256 + threadIdx.x;   // 8192 outputs
    int d = gid >> 6;                            // hidden unit (wave-uniform)
    int r = gid & 63;                            // z row
    const float* w = W1 + d * (ZD_ + PD_);
    const float* z = z_all + r * ZD_;
    float acc = b1[d];
    #pragma unroll 8
    for (int c = 0; c < ZD_; ++c) acc += z[c] * w[c];
    #pragma unroll
    for (int c = 0; c < PD_; ++c) acc += pde[c] * w[ZD_ + c];
    hidT[d * 64 + r] = fmaxf(acc, 0.0f);
}

// ---------------------------------------------------------------------------
// K1 fused (R4 structure — best verified, 137.4 µs total):
// block = (ob, ibp8), n0 = ob*576 + ibp*72 (72 W2 rows = 8 ib x 9 k).
// 256 threads: thread = (cg 0..15, ibl 0..7, ks 0..1).
//   Register tile: 4 cells x 9 k-rows over the ks-th K-half. Per 4-c chunk:
//   4 b128 (hidT, stride 68) + 9 b128 (W2, stride 132 — pad REQUIRED:
//   132/4 ≡ 1 mod 32 rotates rows across banks; unpadded 128 puts all ibl
//   addresses on one 4-bank group = 4-way conflict, the R6 regression).
// LDS phase 1: s_w2[72][132] (38.0 KB) + s_hT[128][68] (34.8 KB) = 72.8 KB
//   -> 2 blocks/CU, 8 waves/CU.
// LDS phase 2 (aliased after barrier): s_exe[64][73] + s_red[128][37] in the
//   s_w2 region; s_un[64][72] in the s_hT region.
// K-split combine: ks=1 waves dump acc to s_red; ks=0 waves add partner
//   partial + write s_exe. Branches wave-uniform.
// Epilogue: 64 runs x 162 float4, coalesced 16B-aligned stores.
// ---------------------------------------------------------------------------
#define SMEM_FLOATS 18208   // 72,832 bytes

__global__ __launch_bounds__(256) void fused_kernel(
        const float* __restrict__ hidT,
        const float* __restrict__ W2,
        const float* __restrict__ b2,
        const float* __restrict__ unet,
        float* __restrict__ out) {
    __shared__ __align__(16) float smem[SMEM_FLOATS];
    float* s_w2 = smem;            // 72*132 = 9504 floats
    float* s_hT = smem + 9504;     // 128*68 = 8704 floats

    int tid = threadIdx.x;
    int b   = blockIdx.x;
    int ob  = b >> 3;              // 0..63
    int ibp = b & 7;               // 0..7
    int n0  = ob * 576 + ibp * 72;

    // --- stage W2: 72 contiguous rows = 2304 float4, 9 per thread ---
    const float4* g4 = reinterpret_cast<const float4*>(W2 + (size_t)n0 * DH_);
    #pragma unroll
    for (int t = 0; t < 9; ++t) {
        int j   = t * 256 + tid;
        int row = j >> 5;          // 0..71
        int c4  = j & 31;
        *reinterpret_cast<float4*>(&s_w2[row * 132 + c4 * 4]) = g4[j];
    }
    // --- stage hidT: 8192 floats = 2048 float4, 8 per thread ---
    const float4* h4g = reinterpret_cast<const float4*>(hidT);
    #pragma unroll
    for (int t = 0; t < 8; ++t) {
        int j  = t * 256 + tid;
        int d  = j >> 4;           // k index 0..127
        int r4 = j & 15;           // cell-quad
        *reinterpret_cast<float4*>(&s_hT[d * 68 + r4 * 4]) = h4g[j];
    }

    int cg  = tid & 15;            // cells 4cg..4cg+3
    int ibl = (tid >> 4) & 7;      // local ib
    int ks  = tid >> 7;            // k-half (wave-uniform)

    float4 acc[9];
    if (ks == 0) {
        #pragma unroll
        for (int kk = 0; kk < 9; ++kk) {
            float bv = b2[n0 + ibl * 9 + kk];
            acc[kk] = make_float4(bv, bv, bv, bv);
        }
    } else {
        #pragma unroll
        for (int kk = 0; kk < 9; ++kk) acc[kk] = make_float4(0.f, 0.f, 0.f, 0.f);
    }
    __syncthreads();

    // --- dot: 16 chunks of 4 c-values over this thread's K-half ---
    const float* wbase = s_w2 + ibl * 9 * 132 + ks * 64;
    const float* hbase = s_hT + (size_t)ks * 64 * 68 + 4 * cg;
    #pragma unroll 2
    for (int cc = 0; cc < 64; cc += 4) {
        float4 h0 = *reinterpret_cast<const float4*>(&hbase[(cc + 0) * 68]);
        float4 h1 = *reinterpret_cast<const float4*>(&hbase[(cc + 1) * 68]);
        float4 h2 = *reinterpret_cast<const float4*>(&hbase[(cc + 2) * 68]);
        float4 h3 = *reinterpret_cast<const float4*>(&hbase[(cc + 3) * 68]);
        #pragma unroll
        for (int kk = 0; kk < 9; ++kk) {
            float4 w = *reinterpret_cast<const float4*>(&wbase[kk * 132 + cc]);
            acc[kk].x += h0.x * w.x + h1.x * w.y + h2.x * w.z + h3.x * w.w;
            acc[kk].y += h0.y * w.x + h1.y * w.y + h2.y * w.z + h3.y * w.w;
            acc[kk].z += h0.z * w.x + h1.z * w.y + h2.z * w.z + h3.z * w.w;
            acc[kk].w += h0.w * w.x + h1.w * w.y + h2.w * w.z + h3.w * w.w;
        }
    }
    __syncthreads();   // all s_w2 / s_hT reads complete -> safe to alias

    float* s_exe = smem;           // 64*73 = 4672 floats
    float* s_red = smem + 4672;    // 128*37 = 4736 floats (ends 9408 < 9504)
    float* s_un  = smem + 9504;    // 64*72 = 4608 floats

    if (ks == 1) {                 // waves 2,3: dump partials
        int slot = tid & 127;
        #pragma unroll
        for (int kk = 0; kk < 9; ++kk) {
            s_red[slot * 37 + 0 * 9 + kk] = acc[kk].x;
            s_red[slot * 37 + 1 * 9 + kk] = acc[kk].y;
            s_red[slot * 37 + 2 * 9 + kk] = acc[kk].z;
            s_red[slot * 37 + 3 * 9 + kk] = acc[kk].w;
        }
    }
    // stage unet (all threads): 64 cells x 18 float4
    for (int j = tid; j < 1152; j += 256) {
        int cell = j / 18;
        int q    = j - cell * 18;
        int hh = cell >> 3, kb = cell & 7;
        size_t gb = ((size_t)((hh * 64 + ob) * 512 + kb * 64 + ibp * 8)) * 9;
        *reinterpret_cast<float4*>(&s_un[cell * 72 + q * 4]) =
            *reinterpret_cast<const float4*>(unet + gb + q * 4);
    }
    __syncthreads();

    if (ks == 0) {                 // waves 0,1: combine + write s_exe
        #pragma unroll
        for (int kk = 0; kk < 9; ++kk) {
            int col = ibl * 9 + kk;
            s_exe[(4 * cg + 0) * 73 + col] = acc[kk].x + s_red[tid * 37 + 0 * 9 + kk];
            s_exe[(4 * cg + 1) * 73 + col] = acc[kk].y + s_red[tid * 37 + 1 * 9 + kk];
            s_exe[(4 * cg + 2) * 73 + col] = acc[kk].z + s_red[tid * 37 + 2 * 9 + kk];
            s_exe[(4 * cg + 3) * 73 + col] = acc[kk].w + s_red[tid * 37 + 3 * 9 + kk];
        }
    }
    __syncthreads();

    // --- epilogue: 64 runs x 162 float4, coalesced stores ---
    for (int idx = tid; idx < 10368; idx += 256) {
        int cell = idx / 162;
        int q    = idx - cell * 162;
        float4 v;
        float* vp = &v.x;
        #pragma unroll
        for (int j2 = 0; j2 < 4; ++j2) {
            int e    = q * 4 + j2;         // 0..647 within run
            int ibl2 = e / 81;
            int rem  = e - ibl2 * 81;
            int k    = rem / 9;
            int l    = rem - k * 9;
            vp[j2] = s_exe[cell * 73 + ibl2 * 9 + k]
                   * s_un [cell * 72 + ibl2 * 9 + l];
        }
        int hh = cell >> 3, kb = cell & 7;
        size_t gb = ((size_t)((hh * 64 + ob) * 512 + kb * 64 + ibp * 8)) * 81;
        reinterpret_cast<float4*>(out + gb)[q] = v;   // 16B-aligned
    }
}

// ---------------------------------------------------------------------------
extern "C" void kernel_launch(void* const* d_in, const int* in_sizes, int n_in,
                              void* d_out, int out_size, void* d_ws, size_t ws_size,
                              hipStream_t stream) {
    const float* z_all = (const float*)d_in[0];  // [64,64]
    const float* W1    = (const float*)d_in[1];  // [128,80]
    const float* b1    = (const float*)d_in[2];  // [128]
    const float* W2    = (const float*)d_in[3];  // [36864,128]
    const float* b2    = (const float*)d_in[4];  // [36864]
    const float* unet  = (const float*)d_in[5];  // [512,512,9]
    const float* pde   = (const float*)d_in[6];  // [16]
    float* out = (float*)d_out;                  // [512,512,9,9]

    float* hidT = (float*)d_ws;                  // 8192 floats, [128][64]

    hid_kernel<<<32, 256, 0, stream>>>(z_all, W1, b1, pde, hidT);
    fused_kernel<<<512, 256, 0, stream>>>(hidT, W2, b2, unet, out);
}